// Round 7
// baseline (27010.806 us; speedup 1.0000x reference)
//
#include <hip/hip_runtime.h>

#define NHID 512
#define NXW  128
#define TLEN 16384
#define STEPS (TLEN - NXW)      // 16256
#define G    32                 // persistent workgroups
#define B    512                // 8 waves per WG
#define RPW  16                 // hidden rows owned per WG
#define RSLOTS 8                // sync ring depth (32 KB -> IC/L2-hot)

#define FOR4(M)  M(0) M(1) M(2) M(3)
#define FOR16(M) M(0) M(1) M(2) M(3) M(4) M(5) M(6) M(7) \
                 M(8) M(9) M(10) M(11) M(12) M(13) M(14) M(15)

__device__ __forceinline__ float sigmoid_f(float v) { return 1.f / (1.f + __expf(-v)); }
__device__ __forceinline__ float tanh_f(float v)    { return 1.f - 2.f / (1.f + __expf(2.f * v)); }

// AGPR pinning: storage class "a" = AGPR. volatile write pre-loop (cannot be
// rematerialized), volatile read per use in-loop (cannot be hoisted back into
// a big live range -> allocator can never spill these to memory).
#define AWR(dst, src) asm volatile("v_accvgpr_write_b32 %0, %1" : "=a"(dst) : "v"(src));
#define ARD(dst, src) asm volatile("v_accvgpr_read_b32 %0, %1" : "=v"(dst) : "a"(src));

// ---------------------------------------------------------------------------
// R6 skeleton + AGPR-resident U weights.
// WG g owns rows [g*16, g*16+16). 8 waves = 8 k-slices of 64.
// Lane l = output (gate q=l>>4, row g*16+(l&15)); wave w polls h-slice
// [w*64, w*64+64) of the hot ring (tag-validated {tag,h} 8B words).
// ---------------------------------------------------------------------------
__launch_bounds__(B, 2)
__global__ void lstm_persistent(
    const float* x,
    const float* Wf, const float* Uf, const float* bf,
    const float* Wi, const float* Ui, const float* bi,
    const float* Wo, const float* Uo, const float* bo,
    const float* Wc, const float* Uc, const float* bc,
    unsigned long long* ring,     // [RSLOTS][NHID] packed {tag,h}
    float* h_hist)                // [STEPS][NHID] for mu only
{
    __shared__ float x_win[256];                    // x ring: refill every 128 steps
    __shared__ __align__(16) float h_buf[8][64];    // per-wave h-slice staging
    __shared__ float partials[2][B];                // double-buffered

    const int tid = threadIdx.x;
    const int g   = blockIdx.x;
    const int w   = tid >> 6;            // wave = k-slice 0..7
    const int l   = tid & 63;            // output 0..63
    const int q   = l >> 4;              // gate 0=f 1=i 2=o 3=c
    const int row = g * RPW + (l & 15);

    const float* Utab[4] = {Uf, Ui, Uo, Uc};
    const float* Wtab[4] = {Wf, Wi, Wo, Wc};
    const float* Btab[4] = {bf, bi, bo, bc};

    // ---- U weights: 64 floats -> 64 AGPRs (guaranteed loop-resident) ----
    const float4* Up = (const float4*)(Utab[q] + (size_t)row * NHID + w * 64);
    #define LOADU(i) float a##i##x, a##i##y, a##i##z, a##i##w;              \
        { float4 tmp = Up[i];                                               \
          AWR(a##i##x, tmp.x) AWR(a##i##y, tmp.y)                           \
          AWR(a##i##z, tmp.z) AWR(a##i##w, tmp.w) }
    FOR16(LOADU)

    // W weights: 16 floats, stay in VGPRs
    const float4* Wp = (const float4*)(Wtab[q] + row * NXW + w * 16);
    #define DECLW(i) float4 wv##i = Wp[i];
    FOR4(DECLW)
    #define PIN(r) asm volatile("" : "+v"(r.x), "+v"(r.y), "+v"(r.z), "+v"(r.w));
    #define PINW(i) PIN(wv##i)
    FOR4(PINW)

    float bias = 0.f, c_prev = 0.f;
    if (w == 0) bias = Btab[q][row];

    // who writes h_hist: WG g stores its own 16 rows from the polled value
    const bool hist_writer = (w == (g >> 2)) && ((l >> 4) == (g & 3));

    h_buf[w][l] = 0.f;                   // h[-1] = 0 (own wave reads only)

    for (int t = 0; t < STEPS; ++t) {
        if ((t & 127) == 0) {            // x window refill (covers x[t..t+255])
            __syncthreads();
            if (tid < 256) {
                int gi = t + tid;
                x_win[tid] = (gi < TLEN) ? x[gi] : 0.f;
            }
            __syncthreads();
        }

        // x-projection partial (independent of h -> overlaps producer latency)
        float xacc = 0.f;
        {
            const int xb = (t & 127) + w * 16;
            #define XF(i) xacc += wv##i.x * x_win[xb + 4*i]     \
                                + wv##i.y * x_win[xb + 4*i + 1] \
                                + wv##i.z * x_win[xb + 4*i + 2] \
                                + wv##i.w * x_win[xb + 4*i + 3];
            FOR4(XF)
        }

        // poll own 8B ring word of h[t-1]: hot line, tag-validated
        float hval = 0.f;
        if (t > 0) {
            const unsigned long long* src =
                ring + ((size_t)((t - 1) & (RSLOTS - 1)) << 9) + (w * 64 + l);
            const unsigned want = (unsigned)(t - 1);
            unsigned long long vv; int guard = 0;
            do {
                vv = __hip_atomic_load(src, __ATOMIC_RELAXED, __HIP_MEMORY_SCOPE_AGENT);
            } while ((unsigned)(vv >> 32) != want && ++guard < (1 << 20));
            hval = __uint_as_float((unsigned)vv);
            h_buf[w][l] = hval;
        }

        // U @ h slice: 64 x (accvgpr_read + fmac), h via wave-uniform LDS reads
        float acc = xacc;
        const float4* hb4 = (const float4*)h_buf[w];
        #define UF(i) { float4 hv = hb4[i]; float t0, t1, t2, t3;           \
                        ARD(t0, a##i##x) ARD(t1, a##i##y)                   \
                        ARD(t2, a##i##z) ARD(t3, a##i##w)                   \
                        acc += t0 * hv.x + t1 * hv.y                        \
                             + t2 * hv.z + t3 * hv.w; }
        FOR16(UF)
        partials[t & 1][(w << 6) | l] = acc;

        // mu-history store for step t-1, off the critical path (sinkable)
        if (t > 0 && hist_writer)
            h_hist[(size_t)(t - 1) * NHID + w * 64 + l] = hval;

        __syncthreads();                 // the ONE per-step barrier

        // wave-0 tail: reduce 8 k-slices, activate, combine, publish to ring
        if (w == 0) {
            const float* p = partials[t & 1];
            float pre = acc + bias;
            #pragma unroll
            for (int s2 = 1; s2 < 8; ++s2) pre += p[s2 * 64 + l];
            float a = (l < 48) ? sigmoid_f(pre) : tanh_f(pre);   // f,i,o / g
            float ai = __shfl(a, l + 16, 64);
            float ao = __shfl(a, l + 32, 64);
            float ag = __shfl(a, l + 48, 64);
            if (l < 16) {
                float c = a * c_prev + ai * ag;
                c_prev = c;
                float h = ao * tanh_f(c);
                unsigned long long pv =
                    ((unsigned long long)(unsigned)t << 32)
                    | (unsigned long long)__float_as_uint(h);
                __hip_atomic_store(
                    ring + ((size_t)(t & (RSLOTS - 1)) << 9) + row, pv,
                    __ATOMIC_RELAXED, __HIP_MEMORY_SCOPE_AGENT);
                if (t == STEPS - 1)      // last h never polled: store directly
                    h_hist[(size_t)t * NHID + row] = h;
            }
        }
    }
}

// ---------------------------------------------------------------------------
// epilogue: mu[t] = Ahy . h_hist[t] + by   (one wave per t)
// ---------------------------------------------------------------------------
__global__ void mu_kernel(const float* __restrict__ h_hist,
                          const float* __restrict__ Ahy,
                          const float* __restrict__ by,
                          float* __restrict__ outp, int steps)
{
    int wave = threadIdx.x >> 6;
    int lane = threadIdx.x & 63;
    int t = blockIdx.x * 4 + wave;
    if (t >= steps) return;
    const float* h = h_hist + (size_t)t * NHID;
    float p = 0.f;
    #pragma unroll
    for (int e = 0; e < 8; e++)
        p += Ahy[e * 64 + lane] * h[e * 64 + lane];
    #pragma unroll
    for (int off = 32; off; off >>= 1) p += __shfl_down(p, off, 64);
    if (lane == 0) outp[t] = p + by[0];
}

// ---------------------------------------------------------------------------
extern "C" void kernel_launch(void* const* d_in, const int* in_sizes, int n_in,
                              void* d_out, int out_size, void* d_ws, size_t ws_size,
                              hipStream_t stream)
{
    const float* x  = (const float*)d_in[0];
    const float* Wf = (const float*)d_in[1];
    const float* Uf = (const float*)d_in[2];
    const float* bf = (const float*)d_in[3];
    const float* Wi = (const float*)d_in[4];
    const float* Ui = (const float*)d_in[5];
    const float* bi = (const float*)d_in[6];
    const float* Wo = (const float*)d_in[7];
    const float* Uo = (const float*)d_in[8];
    const float* bo = (const float*)d_in[9];
    const float* Wc = (const float*)d_in[10];
    const float* Uc = (const float*)d_in[11];
    const float* bc = (const float*)d_in[12];
    const float* Ahy = (const float*)d_in[13];
    const float* by  = (const float*)d_in[14];

    unsigned long long* ring = (unsigned long long*)d_ws;        // 32 KB
    float* h_hist = (float*)((char*)d_ws + RSLOTS * NHID * 8);   // ~33.3 MB

    lstm_persistent<<<G, B, 0, stream>>>(x, Wf, Uf, bf, Wi, Ui, bi,
                                         Wo, Uo, bo, Wc, Uc, bc, ring, h_hist);
    int muBlocks = (STEPS + 3) / 4;
    mu_kernel<<<muBlocks, 256, 0, stream>>>(h_hist, Ahy, by, (float*)d_out, STEPS);
}